// Round 4
// baseline (829.735 us; speedup 1.0000x reference)
//
#include <hip/hip_runtime.h>
#include <hip/hip_fp16.h>
#include <math.h>

#define B_ 128
#define T_ 256
#define E_ 300
#define H_ 256
#define N5_ 1280
#define NSTEPS 511
#define DMAX 8

typedef _Float16 half8_t __attribute__((ext_vector_type(8)));
typedef float float4_t __attribute__((ext_vector_type(4)));
typedef unsigned int u4v __attribute__((ext_vector_type(4)));

// precise versions (k1 epilogue — feeds the whole recurrence, keep accurate)
__device__ __forceinline__ float sigm_p(float x){ return 1.f/(1.f + expf(-x)); }
// fast versions (k3 serial tail only)
__device__ __forceinline__ float sigm(float x){ return __builtin_amdgcn_rcpf(1.f + __expf(-x)); }
__device__ __forceinline__ float ftanh(float x){
  float xc = fminf(15.f, fmaxf(-15.f, x));
  float e = __expf(-2.f*xc);
  return (1.f - e) * __builtin_amdgcn_rcpf(1.f + e);
}

__device__ __forceinline__ int dot4(int a, int b, int c){
#if __has_builtin(__builtin_amdgcn_sdot4)
  return __builtin_amdgcn_sdot4(a, b, c, false);
#else
  int d;
  asm("v_dot4_i32_i8 %0, %1, %2, %3" : "=v"(d) : "v"(a), "v"(b), "v"(c));
  return d;
#endif
}

// ---------------------------------------------------------------------------
// K0a: per-column absmax scale for hl-part of Wr (rows 0..255).
// ---------------------------------------------------------------------------
__global__ __launch_bounds__(64) void k0a_scale(const float* __restrict__ Wr,
    float* __restrict__ scales){
  const int n = blockIdx.x, t = threadIdx.x;
  float m = 0.f;
  #pragma unroll
  for (int j=0;j<4;j++) m = fmaxf(m, fabsf(Wr[(size_t)(t+64*j)*N5_ + n]));
  #pragma unroll
  for (int off=32; off; off>>=1) m = fmaxf(m, __shfl_xor(m, off, 64));
  if (t==0) scales[n] = fmaxf(m, 1e-20f) * (1.f/127.f);
}

// ---------------------------------------------------------------------------
// K0b: quantize hl-part of Wr (rows 0..255) into dot4 layout:
//   W8[col][kd] (u32) packs Wr[4kd+j][col], j=0..3, col-scaled int8.
//   col in [0,1280), kd in [0,64). 81920 dwords = 320 KB.
// ---------------------------------------------------------------------------
__global__ __launch_bounds__(256) void k0b_quant(const float* __restrict__ Wr,
    const float* __restrict__ scales, unsigned* __restrict__ W8){
  int idx = blockIdx.x*256 + threadIdx.x;
  if (idx >= 81920) return;
  const int col = idx >> 6, kd = idx & 63;
  const float inv = 1.f / scales[col];
  unsigned acc = 0;
  #pragma unroll
  for (int j=0;j<4;j++){
    float wv = Wr[(size_t)(4*kd + j)*N5_ + col];
    int q = (int)rintf(wv * inv);
    q = q > 127 ? 127 : (q < -127 ? -127 : q);
    acc |= ((unsigned)(q & 255)) << (8*j);
  }
  W8[idx] = acc;
}

// ---------------------------------------------------------------------------
// K1: fused projection GEMM (unchanged).
// ---------------------------------------------------------------------------
__global__ __launch_bounds__(256) void k1_proj(
    const float* __restrict__ x, const float* __restrict__ Wp, const float* __restrict__ bp,
    const float* __restrict__ Wg, const float* __restrict__ bg,
    _Float16* __restrict__ h2, _Float16* __restrict__ c2){
  __shared__ __align__(16) _Float16 As [64*32];
  __shared__ __align__(16) _Float16 BsP[64*32];
  __shared__ __align__(16) _Float16 BsG[64*32];
  const int tid = threadIdx.x;
  const int row0 = blockIdx.x * 64;
  const int n0   = blockIdx.y * 64;
  const int wave = tid >> 6, lane = tid & 63;
  const int ml = lane & 15, quad = lane >> 4;
  float4_t accP[4], accG[4];
  #pragma unroll
  for (int i=0;i<4;i++){ accP[i]=(float4_t)(0.f); accG[i]=(float4_t)(0.f); }
  const int ar = tid >> 2, ak = (tid & 3) * 8;
  const int bk = tid >> 3, bn = (tid & 7) * 8;
  for (int kk = 0; kk < E_; kk += 32){
    __syncthreads();
    {
      const float* src = x + (size_t)(row0 + ar)*E_ + kk + ak;
      float v[8];
      #pragma unroll
      for (int q=0;q<2;q++){
        if (kk + ak + q*4 + 4 <= E_){
          float4_t f = *(const float4_t*)(src + q*4);
          v[q*4+0]=f.x; v[q*4+1]=f.y; v[q*4+2]=f.z; v[q*4+3]=f.w;
        } else {
          #pragma unroll
          for (int j=0;j<4;j++){ int kg = kk+ak+q*4+j; v[q*4+j] = (kg<E_) ? src[q*4+j] : 0.f; }
        }
      }
      #pragma unroll
      for (int j=0;j<8;j++) As[ar*32 + ak + j] = (_Float16)v[j];
    }
    {
      const int kg = kk + bk;
      if (kg < E_){
        const float* sp_ = Wp + (size_t)kg*H_ + n0 + bn;
        const float* sg_ = Wg + (size_t)kg*H_ + n0 + bn;
        float4_t p0 = *(const float4_t*)sp_, p1 = *(const float4_t*)(sp_+4);
        float4_t g0 = *(const float4_t*)sg_, g1 = *(const float4_t*)(sg_+4);
        float pv[8]={p0.x,p0.y,p0.z,p0.w,p1.x,p1.y,p1.z,p1.w};
        float gv[8]={g0.x,g0.y,g0.z,g0.w,g1.x,g1.y,g1.z,g1.w};
        #pragma unroll
        for (int j=0;j<8;j++){ BsP[(bn+j)*32+bk]=(_Float16)pv[j]; BsG[(bn+j)*32+bk]=(_Float16)gv[j]; }
      } else {
        #pragma unroll
        for (int j=0;j<8;j++){ BsP[(bn+j)*32+bk]=(_Float16)0.f; BsG[(bn+j)*32+bk]=(_Float16)0.f; }
      }
    }
    __syncthreads();
    half8_t a = *(const half8_t*)&As[(wave*16 + ml)*32 + quad*8];
    #pragma unroll
    for (int nt=0; nt<4; nt++){
      half8_t b1 = *(const half8_t*)&BsP[(nt*16 + ml)*32 + quad*8];
      accP[nt] = __builtin_amdgcn_mfma_f32_16x16x32_f16(a, b1, accP[nt], 0,0,0);
      half8_t b2 = *(const half8_t*)&BsG[(nt*16 + ml)*32 + quad*8];
      accG[nt] = __builtin_amdgcn_mfma_f32_16x16x32_f16(a, b2, accG[nt], 0,0,0);
    }
  }
  #pragma unroll
  for (int nt=0; nt<4; nt++){
    #pragma unroll
    for (int r=0;r<4;r++){
      int row = row0 + wave*16 + quad*4 + r;
      int col = n0 + nt*16 + ml;
      float c = accP[nt][r] + bp[col];
      float g = accG[nt][r] + bg[col];
      float h = sigm_p(g) * tanhf(c);
      size_t o = (size_t)row*H_ + col;
      c2[o] = (_Float16)c;
      h2[o] = (_Float16)h;
    }
  }
}

// ---------------------------------------------------------------------------
// K2: R = h_buf @ Wr[256:512,:] + br -> f16 R2 (unchanged)
// ---------------------------------------------------------------------------
__global__ __launch_bounds__(256) void k2_rproj(
    const _Float16* __restrict__ h2, const float* __restrict__ Wr, const float* __restrict__ br,
    _Float16* __restrict__ R2){
  __shared__ __align__(16) _Float16 As[64*32];
  __shared__ __align__(16) _Float16 Bs[64*32];
  const int tid = threadIdx.x;
  const int row0 = blockIdx.x*64, n0 = blockIdx.y*64;
  const int wave = tid>>6, lane = tid&63, ml = lane&15, quad = lane>>4;
  float4_t acc[4];
  #pragma unroll
  for (int i=0;i<4;i++) acc[i]=(float4_t)(0.f);
  const int ar = tid>>2, ak = (tid&3)*8;
  const int bk = tid>>3, bn = (tid&7)*8;
  for (int kk=0; kk<H_; kk+=32){
    __syncthreads();
    *(half8_t*)&As[ar*32+ak] = *(const half8_t*)(h2 + (size_t)(row0+ar)*H_ + kk + ak);
    {
      const float* src = Wr + (size_t)(256 + kk + bk)*N5_ + n0 + bn;
      float4_t f0 = *(const float4_t*)src, f1 = *(const float4_t*)(src+4);
      float v[8]={f0.x,f0.y,f0.z,f0.w,f1.x,f1.y,f1.z,f1.w};
      #pragma unroll
      for (int j=0;j<8;j++) Bs[(bn+j)*32+bk] = (_Float16)v[j];
    }
    __syncthreads();
    half8_t a = *(const half8_t*)&As[(wave*16+ml)*32 + quad*8];
    #pragma unroll
    for (int nt=0; nt<4; nt++){
      half8_t b8 = *(const half8_t*)&Bs[(nt*16+ml)*32 + quad*8];
      acc[nt] = __builtin_amdgcn_mfma_f32_16x16x32_f16(a, b8, acc[nt], 0,0,0);
    }
  }
  #pragma unroll
  for (int nt=0; nt<4; nt++){
    #pragma unroll
    for (int r=0;r<4;r++){
      int row = row0 + wave*16 + quad*4 + r;
      int col = n0 + nt*16 + ml;
      R2[(size_t)row*N5_ + col] = (_Float16)(acc[nt][r] + br[col]);
    }
  }
}

// ---------------------------------------------------------------------------
// K3 v15: VALU dot4 matvec replaces MFMA. Rationale: hl is a VECTOR, so any
// MFMA shape wastes 15/16 of the M dimension -> per-SIMD matrix-pipe floor
// ~1635 cyc/step regardless of partitioning. v_dot4_i32_i8 has no M waste:
// 320 dot4/lane/step (5 gates x 64 K-dwords) = 640 cyc/SIMD VALU.
//   - 256 threads/block, 1 wave/SIMD, lane <-> column 1:1 (tail is 1:1).
//   - Weights register-resident: wqv[80] u4v = 320 VGPR/lane (one-time load).
//   - Activations: int8 h vector broadcast from LDS, 16x ds_read_b128
//     (all lanes same addr = broadcast, conflict-free), hidden under dots.
//   - Same int8 quantization as MFMA path (same scales, i32 accum) ->
//     identical numerics. cl/cr in regs; single barrier/step; sI8 dbuf.
// Spill signature to watch: WRITE_SIZE (must stay ~1.4KB).
// ---------------------------------------------------------------------------
#define BARRIER() asm volatile("s_waitcnt lgkmcnt(0)\n\ts_barrier" ::: "memory")

// 5-gate dot4 matvec for this lane's column: e0..e4 from act (aw) x weights.
#define DOT_ALL() \
  _Pragma("unroll") \
  for (int kd=0; kd<64; kd++){ \
    const int a = (int)aw[kd>>2][kd&3]; \
    e0 = dot4(a, (int)wqv[    (kd>>2)][kd&3], e0); \
    e1 = dot4(a, (int)wqv[16+(kd>>2)][kd&3], e1); \
    e2 = dot4(a, (int)wqv[32+(kd>>2)][kd&3], e2); \
    e3 = dot4(a, (int)wqv[48+(kd>>2)][kd&3], e3); \
    e4 = dot4(a, (int)wqv[64+(kd>>2)][kd&3], e4); \
  }

// One (reduce, shift) pair. 1-deep prefetch pA (R2 row 254-k consumed at
// pair k; reload rrow=253-IDX, crow=252-IDX). RD/WR = sI8 dbuf slots.
#define PAIR_STEP(IDX, RD, WR) { \
  BARRIER(); \
  float a0=(float)pA0, a1=(float)pA1, a2=(float)pA2, a3=(float)pA3, a4=(float)pA4; \
  const float tc = (float)pAc; \
  const u4v* sRD = (const u4v*)(sI8 + (RD)*H_); \
  u4v aw[16]; \
  _Pragma("unroll") \
  for (int t=0; t<16; t++) aw[t] = sRD[t]; \
  { int rrow = 253-(IDX); if (rrow < 0) rrow = 0; \
    const _Float16* rr = R2 + ((size_t)b*T_ + rrow)*N5_ + tid; \
    pA0=rr[0]; pA1=rr[256]; pA2=rr[512]; pA3=rr[768]; pA4=rr[1024]; \
    int crow = 252-(IDX); if (crow < 0) crow = 0; \
    pAc = c2[((size_t)b*T_ + crow)*H_ + tid]; } \
  int e0=0,e1=0,e2=0,e3=0,e4=0; \
  DOT_ALL() \
  a0 += scf0*(float)e0; a1 += scf1*(float)e1; a2 += scf2*(float)e2; \
  a3 += scf3*(float)e3; a4 += scf4*(float)e4; \
  const float cnew = sigm(a1)*cl + sigm(a2)*cr + sigm(a0)*ftanh(a3); \
  const float hnew = sigm(a4)*ftanh(cnew); \
  sI8[(WR)*H_ + tid] = (char)(int)rintf(hnew*127.f); \
  cl = cnew; cr = tc; \
}

__global__ __launch_bounds__(256, 1) void k3_scan(
    const int* __restrict__ trans, const _Float16* __restrict__ h2, const _Float16* __restrict__ c2,
    const _Float16* __restrict__ R2, const unsigned* __restrict__ W8,
    const float* __restrict__ scales, const float* __restrict__ Wr,
    const float* __restrict__ br, float* __restrict__ out){
  __shared__ float sh_[DMAX*H_];
  __shared__ float sc_[DMAX*H_];
  __shared__ __align__(16) char sI8[DMAX*H_];
  __shared__ int trs[NSTEPS+1];

  const int b = blockIdx.x, tid = threadIdx.x;

  // weights register-resident: 5 gates x 16 u4v (64 K-dwords) = 320 VGPR
  u4v wqv[80];
  #pragma unroll
  for (int g=0; g<5; g++){
    const u4v* src = (const u4v*)(W8 + (size_t)(g*256 + tid)*64);
    #pragma unroll
    for (int t=0; t<16; t++) wqv[g*16 + t] = src[t];
  }

  const float scf0 = scales[tid       ] * (1.f/127.f);
  const float scf1 = scales[tid +  256] * (1.f/127.f);
  const float scf2 = scales[tid +  512] * (1.f/127.f);
  const float scf3 = scales[tid +  768] * (1.f/127.f);
  const float scf4 = scales[tid + 1024] * (1.f/127.f);

  trs[tid] = (tid < NSTEPS) ? trans[(size_t)tid*B_ + b] : 1;
  { int j = 256 + tid; if (j < NSTEPS) trs[j] = trans[(size_t)j*B_ + b]; }
  #pragma unroll
  for (int d=0; d<DMAX; d++){ sh_[d*H_+tid]=0.f; sc_[d*H_+tid]=0.f; sI8[d*H_+tid]=0; }

  // pattern check: S S (R S)* with even steps >=2 reduce, odd steps shift
  int myok = 1;
  { int s = tid;
    if (s < NSTEPS){ int e = (s>=2 && (s&1)==0) ? 1 : 0; if (trs[s]!=e) myok=0; } }
  { int s = tid + 256;
    if (s < NSTEPS){ int e = ((s&1)==0) ? 1 : 0; if (trs[s]!=e) myok=0; } }
  const int ok = __syncthreads_and(myok);   // also orders trs/stack init

  if (ok){
    // ---------------- fast pattern path ----------------
    const size_t hb = (size_t)b*T_*H_;
    // prologue: sI8 slot0 = quant(h255); cl = c255, cr = c254 in regs
    const _Float16 h255 = h2[hb + 255*H_ + tid];
    float cl = (float)c2[hb + 255*H_ + tid];
    float cr = (float)c2[hb + 254*H_ + tid];
    // prefetch pair0 (R2 row 254, token c 253)
    _Float16 pA0,pA1,pA2,pA3,pA4,pAc;
    { const _Float16* rr = R2 + ((size_t)b*T_ + 254)*N5_ + tid;
      pA0=rr[0]; pA1=rr[256]; pA2=rr[512]; pA3=rr[768]; pA4=rr[1024];
      pAc = c2[hb + 253*H_ + tid]; }
    sI8[tid] = (char)(int)rintf((float)h255 * 127.f);
    // 254 full pairs, unrolled x2: even pair reads slot0/writes slot1, odd
    // pair reads slot1/writes slot0
    #pragma unroll 1
    for (int i=0; i<254; i+=2){
      PAIR_STEP(i,   0, 1)
      PAIR_STEP(i+1, 1, 0)
    }
    // final reduce (pair 254: R2 row 0, cr = token 0) — reads slot0
    {
      BARRIER();
      float a0=(float)pA0, a1=(float)pA1, a2=(float)pA2, a3=(float)pA3, a4=(float)pA4;
      const u4v* sRD = (const u4v*)sI8;
      u4v aw[16];
      #pragma unroll
      for (int t=0; t<16; t++) aw[t] = sRD[t];
      int e0=0,e1=0,e2=0,e3=0,e4=0;
      DOT_ALL()
      a0 += scf0*(float)e0; a1 += scf1*(float)e1; a2 += scf2*(float)e2;
      a3 += scf3*(float)e3; a4 += scf4*(float)e4;
      const float cnew = sigm(a1)*cl + sigm(a2)*cr + sigm(a0)*ftanh(a3);
      const float hnew = sigm(a4)*ftanh(cnew);
      out[(size_t)b*H_ + tid] = hnew;
    }
    return;
  }

  // ---------------- generic fallback (direct loads) ----------------
  int sp = 0, bptr = T_, prev_src = -1;
  for (int step=0; step<NSTEPS; step++){
    __syncthreads();
    const int tr = trs[step];
    if (tr == 0){                            // SHIFT (trans uniform per block)
      const int nbp = bptr - 1;
      const int src = nbp > 0 ? nbp : 0;
      const int slot = sp < 0 ? 0 : (sp > DMAX-1 ? DMAX-1 : sp);
      const size_t o = ((size_t)b*T_ + src)*H_ + tid;
      const float wh = (float)h2[o], wc = (float)c2[o];
      sh_[slot*H_+tid] = wh;
      sc_[slot*H_+tid] = wc;
      sI8[slot*H_+tid] = (char)(int)rintf(wh * 127.f);
      sp += 1; bptr = nbp; prev_src = src;
    } else {                                 // REDUCE
      int ir = sp-1 > 0 ? sp-1 : 0;
      int il = sp-2 > 0 ? sp-2 : 0;
      ir = ir > DMAX-1 ? DMAX-1 : ir;
      il = il > DMAX-1 ? DMAX-1 : il;
      const int tg = prev_src;
      const float cl = sc_[il*H_+tid];
      const float cr = sc_[ir*H_+tid];
      const u4v* sRD = (const u4v*)(sI8 + il*H_);
      u4v aw[16];
      #pragma unroll
      for (int t=0; t<16; t++) aw[t] = sRD[t];
      float a0,a1,a2,a3,a4;
      if (tg >= 0){
        const _Float16* rr = R2 + ((size_t)b*T_ + tg)*N5_ + tid;
        a0=(float)rr[0]; a1=(float)rr[256]; a2=(float)rr[512]; a3=(float)rr[768]; a4=(float)rr[1024];
      } else {
        a0=br[tid]; a1=br[tid+256]; a2=br[tid+512]; a3=br[tid+768]; a4=br[tid+1024];
      }
      int e0=0,e1=0,e2=0,e3=0,e4=0;
      DOT_ALL()
      a0 += scf0*(float)e0; a1 += scf1*(float)e1; a2 += scf2*(float)e2;
      a3 += scf3*(float)e3; a4 += scf4*(float)e4;
      if (tg < 0){                           // general hr fallback
        for (int k=0; k<H_; k++){
          const float hrk = sh_[ir*H_+k];
          const float* wr = Wr + (size_t)(256+k)*N5_ + tid;
          a0 += hrk*wr[0]; a1 += hrk*wr[256]; a2 += hrk*wr[512];
          a3 += hrk*wr[768]; a4 += hrk*wr[1024];
        }
      }
      const float cnew = sigm(a1)*cl + sigm(a2)*cr + sigm(a0)*ftanh(a3);
      const float hnew = sigm(a4)*ftanh(cnew);
      const int wq = (int)rintf(hnew * 127.f);
      __syncthreads();
      sh_[il*H_+tid] = hnew;
      sc_[il*H_+tid] = cnew;
      sI8[il*H_+tid] = (char)wq;
      sp -= 1; prev_src = -1;
    }
  }
  __syncthreads();
  int fs = sp-1 > 0 ? sp-1 : 0;
  fs = fs > DMAX-1 ? DMAX-1 : fs;
  out[(size_t)b*H_ + tid] = sh_[fs*H_+tid];
}

// ---------------------------------------------------------------------------
// Workspace layout (bytes):
//   h2     @ 0          : 16,777,216
//   c2     @ 16777216   : 16,777,216
//   R2     @ 33554432   : 83,886,080
//   W8     @ 117440512  : 327,680   (int8 dot4 weights, W8[col][kd])
//   scales @ 117768192  : 5,120
// ---------------------------------------------------------------------------
extern "C" void kernel_launch(void* const* d_in, const int* in_sizes, int n_in,
                              void* d_out, int out_size, void* d_ws, size_t ws_size,
                              hipStream_t stream){
  const float* x    = (const float*)d_in[0];
  const int*   trn  = (const int*)  d_in[1];
  const float* Wp   = (const float*)d_in[2];
  const float* bp   = (const float*)d_in[3];
  const float* Wg   = (const float*)d_in[4];
  const float* bg   = (const float*)d_in[5];
  const float* Wr   = (const float*)d_in[6];
  const float* br   = (const float*)d_in[7];
  float* out = (float*)d_out;
  char* w = (char*)d_ws;
  _Float16* h2   = (_Float16*)(w);
  _Float16* c2   = (_Float16*)(w + (size_t)16777216);
  _Float16* R2   = (_Float16*)(w + (size_t)33554432);
  unsigned* W8   = (unsigned*)(w + (size_t)117440512);
  float*    scl  = (float*)   (w + (size_t)117768192);

  hipLaunchKernelGGL(k0a_scale, dim3(1280),    dim3(64),  0, stream, Wr, scl);
  hipLaunchKernelGGL(k0b_quant, dim3(320),     dim3(256), 0, stream, Wr, scl, W8);
  hipLaunchKernelGGL(k1_proj,   dim3(512, 4),  dim3(256), 0, stream, x, Wp, bp, Wg, bg, h2, c2);
  hipLaunchKernelGGL(k2_rproj,  dim3(512, 20), dim3(256), 0, stream, h2, Wr, br, R2);
  hipLaunchKernelGGL(k3_scan,   dim3(128),     dim3(256), 0, stream, trn, h2, c2, R2, W8, scl, Wr, br, out);
}

// Round 6
// 543.554 us; speedup vs baseline: 1.5265x; 1.5265x over previous
//
#include <hip/hip_runtime.h>
#include <hip/hip_fp16.h>
#include <math.h>

#define B_ 128
#define T_ 256
#define E_ 300
#define H_ 256
#define N5_ 1280
#define NSTEPS 511
#define DMAX 8

typedef _Float16 half8_t __attribute__((ext_vector_type(8)));
typedef float float4_t __attribute__((ext_vector_type(4)));
typedef unsigned int u4v __attribute__((ext_vector_type(4)));

// precise versions (k1 epilogue — feeds the whole recurrence, keep accurate)
__device__ __forceinline__ float sigm_p(float x){ return 1.f/(1.f + expf(-x)); }
// fast versions (k3 serial tail only)
__device__ __forceinline__ float sigm(float x){ return __builtin_amdgcn_rcpf(1.f + __expf(-x)); }
__device__ __forceinline__ float ftanh(float x){
  float xc = fminf(15.f, fmaxf(-15.f, x));
  float e = __expf(-2.f*xc);
  return (1.f - e) * __builtin_amdgcn_rcpf(1.f + e);
}

__device__ __forceinline__ int dot4(int a, int b, int c){
#if __has_builtin(__builtin_amdgcn_sdot4)
  return __builtin_amdgcn_sdot4(a, b, c, false);
#else
  int d;
  asm("v_dot4_i32_i8 %0, %1, %2, %3" : "=v"(d) : "v"(a), "v"(b), "v"(c));
  return d;
#endif
}

// ---------------------------------------------------------------------------
// K0a: per-column absmax scale for hl-part of Wr (rows 0..255).
// ---------------------------------------------------------------------------
__global__ __launch_bounds__(64) void k0a_scale(const float* __restrict__ Wr,
    float* __restrict__ scales){
  const int n = blockIdx.x, t = threadIdx.x;
  float m = 0.f;
  #pragma unroll
  for (int j=0;j<4;j++) m = fmaxf(m, fabsf(Wr[(size_t)(t+64*j)*N5_ + n]));
  #pragma unroll
  for (int off=32; off; off>>=1) m = fmaxf(m, __shfl_xor(m, off, 64));
  if (t==0) scales[n] = fmaxf(m, 1e-20f) * (1.f/127.f);
}

// ---------------------------------------------------------------------------
// K0b: quantize hl-part of Wr (rows 0..255) into dot4 layout:
//   W8[col][kd] (u32) packs Wr[4kd+j][col], j=0..3, col-scaled int8.
//   col in [0,1280), kd in [0,64). 81920 dwords = 320 KB.
// ---------------------------------------------------------------------------
__global__ __launch_bounds__(256) void k0b_quant(const float* __restrict__ Wr,
    const float* __restrict__ scales, unsigned* __restrict__ W8){
  int idx = blockIdx.x*256 + threadIdx.x;
  if (idx >= 81920) return;
  const int col = idx >> 6, kd = idx & 63;
  const float inv = 1.f / scales[col];
  unsigned acc = 0;
  #pragma unroll
  for (int j=0;j<4;j++){
    float wv = Wr[(size_t)(4*kd + j)*N5_ + col];
    int q = (int)rintf(wv * inv);
    q = q > 127 ? 127 : (q < -127 ? -127 : q);
    acc |= ((unsigned)(q & 255)) << (8*j);
  }
  W8[idx] = acc;
}

// ---------------------------------------------------------------------------
// K1: fused projection GEMM (unchanged).
// ---------------------------------------------------------------------------
__global__ __launch_bounds__(256) void k1_proj(
    const float* __restrict__ x, const float* __restrict__ Wp, const float* __restrict__ bp,
    const float* __restrict__ Wg, const float* __restrict__ bg,
    _Float16* __restrict__ h2, _Float16* __restrict__ c2){
  __shared__ __align__(16) _Float16 As [64*32];
  __shared__ __align__(16) _Float16 BsP[64*32];
  __shared__ __align__(16) _Float16 BsG[64*32];
  const int tid = threadIdx.x;
  const int row0 = blockIdx.x * 64;
  const int n0   = blockIdx.y * 64;
  const int wave = tid >> 6, lane = tid & 63;
  const int ml = lane & 15, quad = lane >> 4;
  float4_t accP[4], accG[4];
  #pragma unroll
  for (int i=0;i<4;i++){ accP[i]=(float4_t)(0.f); accG[i]=(float4_t)(0.f); }
  const int ar = tid >> 2, ak = (tid & 3) * 8;
  const int bk = tid >> 3, bn = (tid & 7) * 8;
  for (int kk = 0; kk < E_; kk += 32){
    __syncthreads();
    {
      const float* src = x + (size_t)(row0 + ar)*E_ + kk + ak;
      float v[8];
      #pragma unroll
      for (int q=0;q<2;q++){
        if (kk + ak + q*4 + 4 <= E_){
          float4_t f = *(const float4_t*)(src + q*4);
          v[q*4+0]=f.x; v[q*4+1]=f.y; v[q*4+2]=f.z; v[q*4+3]=f.w;
        } else {
          #pragma unroll
          for (int j=0;j<4;j++){ int kg = kk+ak+q*4+j; v[q*4+j] = (kg<E_) ? src[q*4+j] : 0.f; }
        }
      }
      #pragma unroll
      for (int j=0;j<8;j++) As[ar*32 + ak + j] = (_Float16)v[j];
    }
    {
      const int kg = kk + bk;
      if (kg < E_){
        const float* sp_ = Wp + (size_t)kg*H_ + n0 + bn;
        const float* sg_ = Wg + (size_t)kg*H_ + n0 + bn;
        float4_t p0 = *(const float4_t*)sp_, p1 = *(const float4_t*)(sp_+4);
        float4_t g0 = *(const float4_t*)sg_, g1 = *(const float4_t*)(sg_+4);
        float pv[8]={p0.x,p0.y,p0.z,p0.w,p1.x,p1.y,p1.z,p1.w};
        float gv[8]={g0.x,g0.y,g0.z,g0.w,g1.x,g1.y,g1.z,g1.w};
        #pragma unroll
        for (int j=0;j<8;j++){ BsP[(bn+j)*32+bk]=(_Float16)pv[j]; BsG[(bn+j)*32+bk]=(_Float16)gv[j]; }
      } else {
        #pragma unroll
        for (int j=0;j<8;j++){ BsP[(bn+j)*32+bk]=(_Float16)0.f; BsG[(bn+j)*32+bk]=(_Float16)0.f; }
      }
    }
    __syncthreads();
    half8_t a = *(const half8_t*)&As[(wave*16 + ml)*32 + quad*8];
    #pragma unroll
    for (int nt=0; nt<4; nt++){
      half8_t b1 = *(const half8_t*)&BsP[(nt*16 + ml)*32 + quad*8];
      accP[nt] = __builtin_amdgcn_mfma_f32_16x16x32_f16(a, b1, accP[nt], 0,0,0);
      half8_t b2 = *(const half8_t*)&BsG[(nt*16 + ml)*32 + quad*8];
      accG[nt] = __builtin_amdgcn_mfma_f32_16x16x32_f16(a, b2, accG[nt], 0,0,0);
    }
  }
  #pragma unroll
  for (int nt=0; nt<4; nt++){
    #pragma unroll
    for (int r=0;r<4;r++){
      int row = row0 + wave*16 + quad*4 + r;
      int col = n0 + nt*16 + ml;
      float c = accP[nt][r] + bp[col];
      float g = accG[nt][r] + bg[col];
      float h = sigm_p(g) * tanhf(c);
      size_t o = (size_t)row*H_ + col;
      c2[o] = (_Float16)c;
      h2[o] = (_Float16)h;
    }
  }
}

// ---------------------------------------------------------------------------
// K2: R = h_buf @ Wr[256:512,:] + br -> f16 R2 (unchanged)
// ---------------------------------------------------------------------------
__global__ __launch_bounds__(256) void k2_rproj(
    const _Float16* __restrict__ h2, const float* __restrict__ Wr, const float* __restrict__ br,
    _Float16* __restrict__ R2){
  __shared__ __align__(16) _Float16 As[64*32];
  __shared__ __align__(16) _Float16 Bs[64*32];
  const int tid = threadIdx.x;
  const int row0 = blockIdx.x*64, n0 = blockIdx.y*64;
  const int wave = tid>>6, lane = tid&63, ml = lane&15, quad = lane>>4;
  float4_t acc[4];
  #pragma unroll
  for (int i=0;i<4;i++) acc[i]=(float4_t)(0.f);
  const int ar = tid>>2, ak = (tid&3)*8;
  const int bk = tid>>3, bn = (tid&7)*8;
  for (int kk=0; kk<H_; kk+=32){
    __syncthreads();
    *(half8_t*)&As[ar*32+ak] = *(const half8_t*)(h2 + (size_t)(row0+ar)*H_ + kk + ak);
    {
      const float* src = Wr + (size_t)(256 + kk + bk)*N5_ + n0 + bn;
      float4_t f0 = *(const float4_t*)src, f1 = *(const float4_t*)(src+4);
      float v[8]={f0.x,f0.y,f0.z,f0.w,f1.x,f1.y,f1.z,f1.w};
      #pragma unroll
      for (int j=0;j<8;j++) Bs[(bn+j)*32+bk] = (_Float16)v[j];
    }
    __syncthreads();
    half8_t a = *(const half8_t*)&As[(wave*16+ml)*32 + quad*8];
    #pragma unroll
    for (int nt=0; nt<4; nt++){
      half8_t b8 = *(const half8_t*)&Bs[(nt*16+ml)*32 + quad*8];
      acc[nt] = __builtin_amdgcn_mfma_f32_16x16x32_f16(a, b8, acc[nt], 0,0,0);
    }
  }
  #pragma unroll
  for (int nt=0; nt<4; nt++){
    #pragma unroll
    for (int r=0;r<4;r++){
      int row = row0 + wave*16 + quad*4 + r;
      int col = n0 + nt*16 + ml;
      R2[(size_t)row*N5_ + col] = (_Float16)(acc[nt][r] + br[col]);
    }
  }
}

// ---------------------------------------------------------------------------
// K3 v16 (resubmit — R5 was an infra failure, not a kernel failure):
// dot4 matvec with K split across wave halves.
// R4's failure: 320 weight dwords/lane > 256 architected VGPRs (VALU can't
// read AGPRs; 512 is only the unified VGPR+AGPR budget) -> scratch spill.
// Fix: 512 threads, wave w lanes (l&31) own h-column m=w*32+(l&31); l>>5
// selects the K-half. Weights/lane = 5 gates x 32 dwords = 160 VGPR.
// Partial gate sums combined intra-wave via __shfl_xor(e,32) -> no LDS
// exchange, no extra barrier; tail computed redundantly in both halves
// (uniform), only hh==0 writes sI8. Schedule (1 barrier/step, sI8 dbuf,
// 1-deep prefetch) identical to the verified R3 pattern; numerics = R4.
// Spill signature to watch: WRITE_SIZE must be ~1.4KB, VGPR < 256.
// ---------------------------------------------------------------------------
#define BARRIER() asm volatile("s_waitcnt lgkmcnt(0)\n\ts_barrier" ::: "memory")

// 5-gate x my-K-half dot: 160 dot4s. aw[8] = my half of the int8 h vector.
#define DOT_ALL() \
  _Pragma("unroll") \
  for (int t=0; t<8; t++){ \
    _Pragma("unroll") \
    for (int j=0; j<4; j++){ \
      const int a = (int)aw[t][j]; \
      e0 = dot4(a, (int)wqv[   t][j], e0); \
      e1 = dot4(a, (int)wqv[ 8+t][j], e1); \
      e2 = dot4(a, (int)wqv[16+t][j], e2); \
      e3 = dot4(a, (int)wqv[24+t][j], e3); \
      e4 = dot4(a, (int)wqv[32+t][j], e4); \
    } \
  }

#define COMBINE_HALVES() \
  e0 += __shfl_xor(e0, 32, 64); \
  e1 += __shfl_xor(e1, 32, 64); \
  e2 += __shfl_xor(e2, 32, 64); \
  e3 += __shfl_xor(e3, 32, 64); \
  e4 += __shfl_xor(e4, 32, 64);

// One (reduce, shift) pair. 1-deep prefetch pA (R2 row 254-k consumed at
// pair k; reload rrow=253-IDX, crow=252-IDX). RD/WR = sI8 dbuf slots.
#define PAIR_STEP(IDX, RD, WR) { \
  BARRIER(); \
  float a0=(float)pA0, a1=(float)pA1, a2=(float)pA2, a3=(float)pA3, a4=(float)pA4; \
  const float tc = (float)pAc; \
  const u4v* sRD = (const u4v*)(sI8 + (RD)*H_); \
  u4v aw[8]; \
  _Pragma("unroll") \
  for (int t=0; t<8; t++) aw[t] = sRD[hh*8 + t]; \
  { int rrow = 253-(IDX); if (rrow < 0) rrow = 0; \
    const _Float16* rr = R2 + ((size_t)b*T_ + rrow)*N5_ + m; \
    pA0=rr[0]; pA1=rr[256]; pA2=rr[512]; pA3=rr[768]; pA4=rr[1024]; \
    int crow = 252-(IDX); if (crow < 0) crow = 0; \
    pAc = c2[((size_t)b*T_ + crow)*H_ + m]; } \
  int e0=0,e1=0,e2=0,e3=0,e4=0; \
  DOT_ALL() \
  COMBINE_HALVES() \
  a0 += scf0*(float)e0; a1 += scf1*(float)e1; a2 += scf2*(float)e2; \
  a3 += scf3*(float)e3; a4 += scf4*(float)e4; \
  const float cnew = sigm(a1)*cl + sigm(a2)*cr + sigm(a0)*ftanh(a3); \
  const float hnew = sigm(a4)*ftanh(cnew); \
  if (hh == 0) sI8[(WR)*H_ + m] = (char)(int)rintf(hnew*127.f); \
  cl = cnew; cr = tc; \
}

__global__ __launch_bounds__(512, 2) void k3_scan(
    const int* __restrict__ trans, const _Float16* __restrict__ h2, const _Float16* __restrict__ c2,
    const _Float16* __restrict__ R2, const unsigned* __restrict__ W8,
    const float* __restrict__ scales, const float* __restrict__ Wr,
    const float* __restrict__ br, float* __restrict__ out){
  __shared__ float sh_[DMAX*H_];
  __shared__ float sc_[DMAX*H_];
  __shared__ __align__(16) char sI8[DMAX*H_];
  __shared__ int trs[NSTEPS+1];

  const int b = blockIdx.x, tid = threadIdx.x;
  const int lane = tid & 63, w8 = tid >> 6;
  const int m  = w8*32 + (lane & 31);     // h-column 0..255
  const int hh = (lane >> 5) & 1;         // K-half 0/1

  // weights register-resident: 5 gates x 8 u4v (my K-half) = 160 VGPR
  u4v wqv[40];
  #pragma unroll
  for (int g=0; g<5; g++){
    const u4v* src = (const u4v*)(W8 + (size_t)(g*256 + m)*64 + hh*32);
    #pragma unroll
    for (int t=0; t<8; t++) wqv[g*8 + t] = src[t];
  }

  const float scf0 = scales[m       ] * (1.f/127.f);
  const float scf1 = scales[m +  256] * (1.f/127.f);
  const float scf2 = scales[m +  512] * (1.f/127.f);
  const float scf3 = scales[m +  768] * (1.f/127.f);
  const float scf4 = scales[m + 1024] * (1.f/127.f);

  trs[tid] = (tid < NSTEPS) ? trans[(size_t)tid*B_ + b] : 1;
  for (int i = tid; i < DMAX*H_; i += 512){ sh_[i]=0.f; sc_[i]=0.f; sI8[i]=0; }

  // pattern check: S S (R S)* with even steps >=2 reduce, odd steps shift
  int myok = 1;
  if (tid < NSTEPS){ int e = (tid>=2 && (tid&1)==0) ? 1 : 0; if (trs[tid]!=e) myok=0; }
  const int ok = __syncthreads_and(myok);   // also orders trs/stack init

  if (ok){
    // ---------------- fast pattern path ----------------
    const size_t hb = (size_t)b*T_*H_;
    // prologue: sI8 slot0 = quant(h255); cl = c255, cr = c254 in regs
    const _Float16 h255 = h2[hb + 255*H_ + m];
    float cl = (float)c2[hb + 255*H_ + m];
    float cr = (float)c2[hb + 254*H_ + m];
    // prefetch pair0 (R2 row 254, token c 253)
    _Float16 pA0,pA1,pA2,pA3,pA4,pAc;
    { const _Float16* rr = R2 + ((size_t)b*T_ + 254)*N5_ + m;
      pA0=rr[0]; pA1=rr[256]; pA2=rr[512]; pA3=rr[768]; pA4=rr[1024];
      pAc = c2[hb + 253*H_ + m]; }
    if (hh == 0) sI8[m] = (char)(int)rintf((float)h255 * 127.f);
    // 254 full pairs, unrolled x2: even pair reads slot0/writes slot1, odd
    // pair reads slot1/writes slot0
    #pragma unroll 1
    for (int i=0; i<254; i+=2){
      PAIR_STEP(i,   0, 1)
      PAIR_STEP(i+1, 1, 0)
    }
    // final reduce (pair 254: R2 row 0, cr = token 0) — reads slot0
    {
      BARRIER();
      float a0=(float)pA0, a1=(float)pA1, a2=(float)pA2, a3=(float)pA3, a4=(float)pA4;
      const u4v* sRD = (const u4v*)sI8;
      u4v aw[8];
      #pragma unroll
      for (int t=0; t<8; t++) aw[t] = sRD[hh*8 + t];
      int e0=0,e1=0,e2=0,e3=0,e4=0;
      DOT_ALL()
      COMBINE_HALVES()
      a0 += scf0*(float)e0; a1 += scf1*(float)e1; a2 += scf2*(float)e2;
      a3 += scf3*(float)e3; a4 += scf4*(float)e4;
      const float cnew = sigm(a1)*cl + sigm(a2)*cr + sigm(a0)*ftanh(a3);
      const float hnew = sigm(a4)*ftanh(cnew);
      if (hh == 0) out[(size_t)b*H_ + m] = hnew;
    }
    return;
  }

  // ---------------- generic fallback (direct loads) ----------------
  int sp = 0, bptr = T_, prev_src = -1;
  for (int step=0; step<NSTEPS; step++){
    __syncthreads();
    const int tr = trs[step];
    if (tr == 0){                            // SHIFT (trans uniform per block)
      const int nbp = bptr - 1;
      const int src = nbp > 0 ? nbp : 0;
      const int slot = sp < 0 ? 0 : (sp > DMAX-1 ? DMAX-1 : sp);
      const size_t o = ((size_t)b*T_ + src)*H_ + m;
      const float wh = (float)h2[o], wc = (float)c2[o];
      if (hh == 0){
        sh_[slot*H_+m] = wh;
        sc_[slot*H_+m] = wc;
        sI8[slot*H_+m] = (char)(int)rintf(wh * 127.f);
      }
      sp += 1; bptr = nbp; prev_src = src;
    } else {                                 // REDUCE
      int ir = sp-1 > 0 ? sp-1 : 0;
      int il = sp-2 > 0 ? sp-2 : 0;
      ir = ir > DMAX-1 ? DMAX-1 : ir;
      il = il > DMAX-1 ? DMAX-1 : il;
      const int tg = prev_src;
      const float cl = sc_[il*H_+m];
      const float cr = sc_[ir*H_+m];
      const u4v* sRD = (const u4v*)(sI8 + il*H_);
      u4v aw[8];
      #pragma unroll
      for (int t=0; t<8; t++) aw[t] = sRD[hh*8 + t];
      float a0,a1,a2,a3,a4;
      if (tg >= 0){
        const _Float16* rr = R2 + ((size_t)b*T_ + tg)*N5_ + m;
        a0=(float)rr[0]; a1=(float)rr[256]; a2=(float)rr[512]; a3=(float)rr[768]; a4=(float)rr[1024];
      } else {
        a0=br[m]; a1=br[m+256]; a2=br[m+512]; a3=br[m+768]; a4=br[m+1024];
      }
      int e0=0,e1=0,e2=0,e3=0,e4=0;
      DOT_ALL()
      COMBINE_HALVES()
      a0 += scf0*(float)e0; a1 += scf1*(float)e1; a2 += scf2*(float)e2;
      a3 += scf3*(float)e3; a4 += scf4*(float)e4;
      if (tg < 0){                           // general hr fallback
        for (int k=0; k<H_; k++){
          const float hrk = sh_[ir*H_+k];
          const float* wr = Wr + (size_t)(256+k)*N5_ + m;
          a0 += hrk*wr[0]; a1 += hrk*wr[256]; a2 += hrk*wr[512];
          a3 += hrk*wr[768]; a4 += hrk*wr[1024];
        }
      }
      const float cnew = sigm(a1)*cl + sigm(a2)*cr + sigm(a0)*ftanh(a3);
      const float hnew = sigm(a4)*ftanh(cnew);
      const int wq = (int)rintf(hnew * 127.f);
      __syncthreads();
      if (hh == 0){
        sh_[il*H_+m] = hnew;
        sc_[il*H_+m] = cnew;
        sI8[il*H_+m] = (char)wq;
      }
      sp -= 1; prev_src = -1;
    }
  }
  __syncthreads();
  int fs = sp-1 > 0 ? sp-1 : 0;
  fs = fs > DMAX-1 ? DMAX-1 : fs;
  if (hh == 0) out[(size_t)b*H_ + m] = sh_[fs*H_+m];
}

// ---------------------------------------------------------------------------
// Workspace layout (bytes):
//   h2     @ 0          : 16,777,216
//   c2     @ 16777216   : 16,777,216
//   R2     @ 33554432   : 83,886,080
//   W8     @ 117440512  : 327,680   (int8 dot4 weights, W8[col][kd])
//   scales @ 117768192  : 5,120
// ---------------------------------------------------------------------------
extern "C" void kernel_launch(void* const* d_in, const int* in_sizes, int n_in,
                              void* d_out, int out_size, void* d_ws, size_t ws_size,
                              hipStream_t stream){
  const float* x    = (const float*)d_in[0];
  const int*   trn  = (const int*)  d_in[1];
  const float* Wp   = (const float*)d_in[2];
  const float* bp   = (const float*)d_in[3];
  const float* Wg   = (const float*)d_in[4];
  const float* bg   = (const float*)d_in[5];
  const float* Wr   = (const float*)d_in[6];
  const float* br   = (const float*)d_in[7];
  float* out = (float*)d_out;
  char* w = (char*)d_ws;
  _Float16* h2   = (_Float16*)(w);
  _Float16* c2   = (_Float16*)(w + (size_t)16777216);
  _Float16* R2   = (_Float16*)(w + (size_t)33554432);
  unsigned* W8   = (unsigned*)(w + (size_t)117440512);
  float*    scl  = (float*)   (w + (size_t)117768192);

  hipLaunchKernelGGL(k0a_scale, dim3(1280),    dim3(64),  0, stream, Wr, scl);
  hipLaunchKernelGGL(k0b_quant, dim3(320),     dim3(256), 0, stream, Wr, scl, W8);
  hipLaunchKernelGGL(k1_proj,   dim3(512, 4),  dim3(256), 0, stream, x, Wp, bp, Wg, bg, h2, c2);
  hipLaunchKernelGGL(k2_rproj,  dim3(512, 20), dim3(256), 0, stream, h2, Wr, br, R2);
  hipLaunchKernelGGL(k3_scan,   dim3(128),     dim3(512), 0, stream, trn, h2, c2, R2, W8, scl, Wr, br, out);
}